// Round 1
// baseline (641.881 us; speedup 1.0000x reference)
//
#include <hip/hip_runtime.h>

// out = (1/sqrt(N)) * (had_K [12x12]  ⊗  H_1024 natural-order FWHT) applied per row.
// Mix (over chunk index l) and FWHT (over within-chunk index j) commute, so we do
// mix-first in registers, then FWHT via in-reg H4 + 6 shuffle stages + LDS radix-4.

static constexpr int N_COLS = 12288;
static constexpr int KH     = 12;
static constexpr int CHUNK  = 1024;
static constexpr int NC     = 12;          // N_COLS / CHUNK
#define RSQRT_N 9.021097956087904e-03f     // 1/sqrt(12288)

__global__ __launch_bounds__(256, 3)
void had_kernel(const float* __restrict__ x,
                const float* __restrict__ hadK,
                float* __restrict__ out) {
    const int t    = threadIdx.x;    // 0..255
    const int lane = t & 63;         // j bits 2..7
    const int wv   = t >> 6;         // j bits 8..9
    const long row = blockIdx.x;

    const float* __restrict__ xr   = x   + row * (long)N_COLS;
    float*       __restrict__ orow = out + row * (long)N_COLS;

    // ---- load: g[l] = x[row, l*1024 + 4t .. 4t+3] (coalesced dwordx4) ----
    float4 g[NC];
#pragma unroll
    for (int l = 0; l < NC; ++l)
        g[l] = *(const float4*)(xr + l * CHUNK + 4 * t);

    // ---- 12x12 mix in registers: y[k] = sum_l hadK[k,l] * g[l] ----
    float4 y[NC];
#pragma unroll
    for (int k = 0; k < NC; ++k) {
        const float c0 = hadK[k * KH + 0];
        float4 a;
        a.x = c0 * g[0].x; a.y = c0 * g[0].y; a.z = c0 * g[0].z; a.w = c0 * g[0].w;
#pragma unroll
        for (int l = 1; l < NC; ++l) {
            const float c = hadK[k * KH + l];
            a.x = fmaf(c, g[l].x, a.x);
            a.y = fmaf(c, g[l].y, a.y);
            a.z = fmaf(c, g[l].z, a.z);
            a.w = fmaf(c, g[l].w, a.w);
        }
        y[k] = a;
    }

    // ---- FWHT, j bits 0-1: H4 on the float4 components ----
#pragma unroll
    for (int k = 0; k < NC; ++k) {
        const float4 v = y[k];
        const float a = v.x + v.y, b = v.x - v.y;
        const float c = v.z + v.w, d = v.z - v.w;
        y[k].x = a + c; y[k].y = b + d; y[k].z = a - c; y[k].w = b - d;
    }

    // ---- FWHT, j bits 2-7: butterflies across lanes via shfl_xor ----
#pragma unroll
    for (int s = 0; s < 6; ++s) {
        const int m = 1 << s;
        const unsigned sgn = (lane & m) ? 0x80000000u : 0u;  // negate own value on hi side
#pragma unroll
        for (int k = 0; k < NC; ++k) {
            const float4 v = y[k];
            float4 p;
            p.x = __shfl_xor(v.x, m, 64);
            p.y = __shfl_xor(v.y, m, 64);
            p.z = __shfl_xor(v.z, m, 64);
            p.w = __shfl_xor(v.w, m, 64);
            y[k].x = p.x + __uint_as_float(__float_as_uint(v.x) ^ sgn);
            y[k].y = p.y + __uint_as_float(__float_as_uint(v.y) ^ sgn);
            y[k].z = p.z + __uint_as_float(__float_as_uint(v.z) ^ sgn);
            y[k].w = p.w + __uint_as_float(__float_as_uint(v.w) ^ sgn);
        }
    }

    // ---- FWHT, j bits 8-9: radix-4 across the 4 waves via LDS (b128, conflict-free) ----
    __shared__ __align__(16) float lds[NC * CHUNK];   // 48 KB
#pragma unroll
    for (int k = 0; k < NC; ++k)
        *(float4*)&lds[k * CHUNK + 4 * t] = y[k];
    __syncthreads();

    // out_w = sum_{w'} (-1)^{popcount(w & w')} v[w'];  fold 1/sqrt(N) into coeffs.
    // A = own (wave wv), B = wave wv^1, C = wave wv^2, D = wave wv^3:
    //   coeff(A) = (-1)^popc(wv), coeff(B) = (-1)^(wv>>1), coeff(C) = (-1)^(wv&1), coeff(D) = +1
    const float csA = ((__popc(wv) & 1) ? -RSQRT_N : RSQRT_N);
    const float csB = ((wv & 2)         ? -RSQRT_N : RSQRT_N);
    const float csC = ((wv & 1)         ? -RSQRT_N : RSQRT_N);

    const int i1 = (t ^ 64)  * 4;
    const int i2 = (t ^ 128) * 4;
    const int i3 = (t ^ 192) * 4;

#pragma unroll
    for (int k = 0; k < NC; ++k) {
        const float4 A = y[k];
        const float4 B = *(const float4*)&lds[k * CHUNK + i1];
        const float4 C = *(const float4*)&lds[k * CHUNK + i2];
        const float4 D = *(const float4*)&lds[k * CHUNK + i3];
        float4 r;
        r.x = fmaf(csA, A.x, fmaf(csB, B.x, fmaf(csC, C.x, RSQRT_N * D.x)));
        r.y = fmaf(csA, A.y, fmaf(csB, B.y, fmaf(csC, C.y, RSQRT_N * D.y)));
        r.z = fmaf(csA, A.z, fmaf(csB, B.z, fmaf(csC, C.z, RSQRT_N * D.z)));
        r.w = fmaf(csA, A.w, fmaf(csB, B.w, fmaf(csC, C.w, RSQRT_N * D.w)));
        *(float4*)(orow + k * CHUNK + 4 * t) = r;
    }
}

extern "C" void kernel_launch(void* const* d_in, const int* in_sizes, int n_in,
                              void* d_out, int out_size, void* d_ws, size_t ws_size,
                              hipStream_t stream) {
    const float* x    = (const float*)d_in[0];
    const float* hadK = (const float*)d_in[1];
    float* out        = (float*)d_out;
    const int rows = in_sizes[0] / N_COLS;   // 8192
    hipLaunchKernelGGL(had_kernel, dim3(rows), dim3(256), 0, stream, x, hadK, out);
}